// Round 2
// baseline (448.694 us; speedup 1.0000x reference)
//
#include <hip/hip_runtime.h>
#include <math.h>

#define HIDDEN 4096
#define NEXP   128
#define TOPK   8
#define BM     32
#define BKC    64                  // K per staged chunk
#define NCHUNK (HIDDEN / BKC)      // 64
#define SS     132                 // padded stride for score rows in epilogue

// LDS (ushort units): A tiles double-buffered, 3 splits, [32][64] bf16 each.
//   ABUF(b,s) = b*6144 + s*2048.  Total 12288 ushorts = 24 KiB.
//   Epilogue Ss[32][SS] floats (16.9 KiB) aliases the A region.
#define SMEM_USHORT 12288

typedef __attribute__((ext_vector_type(8))) short short8;  // 8 bf16 (4 VGPR)
typedef __attribute__((ext_vector_type(4))) float f32x4;   // MFMA accumulator

__device__ __forceinline__ unsigned pack2(unsigned a, unsigned b) {
  // low ushort = top16 of a, high ushort = top16 of b
  return (a >> 16) | (b & 0xFFFF0000u);
}

// Triple bf16 split: x = hi + mid + lo + O(2^-24 x). hi/mid round-half-away.
struct Split3 { uint4 h, m, l; };
__device__ __forceinline__ Split3 split8(float4 a, float4 b) {
  float x[8] = {a.x, a.y, a.z, a.w, b.x, b.y, b.z, b.w};
  unsigned h[8], m[8], l[8];
#pragma unroll
  for (int j = 0; j < 8; ++j) {
    unsigned u  = __float_as_uint(x[j]);
    unsigned hb = (u + 0x8000u) & 0xFFFF0000u;
    float rh    = x[j] - __uint_as_float(hb);
    unsigned um = __float_as_uint(rh);
    unsigned mb = (um + 0x8000u) & 0xFFFF0000u;
    float rm    = rh - __uint_as_float(mb);
    h[j] = hb; m[j] = mb; l[j] = __float_as_uint(rm);
  }
  Split3 s;
  s.h = make_uint4(pack2(h[0],h[1]), pack2(h[2],h[3]), pack2(h[4],h[5]), pack2(h[6],h[7]));
  s.m = make_uint4(pack2(m[0],m[1]), pack2(m[2],m[3]), pack2(m[4],m[5]), pack2(m[6],m[7]));
  s.l = make_uint4(pack2(l[0],l[1]), pack2(l[2],l[3]), pack2(l[4],l[5]), pack2(l[6],l[7]));
  return s;
}

struct Split3x4 { uint2 h, m, l; };
__device__ __forceinline__ Split3x4 split4(float4 a) {
  float x[4] = {a.x, a.y, a.z, a.w};
  unsigned h[4], m[4], l[4];
#pragma unroll
  for (int j = 0; j < 4; ++j) {
    unsigned u  = __float_as_uint(x[j]);
    unsigned hb = (u + 0x8000u) & 0xFFFF0000u;
    float rh    = x[j] - __uint_as_float(hb);
    unsigned um = __float_as_uint(rh);
    unsigned mb = (um + 0x8000u) & 0xFFFF0000u;
    float rm    = rh - __uint_as_float(mb);
    h[j] = hb; m[j] = mb; l[j] = __float_as_uint(rm);
  }
  Split3x4 s;
  s.h = make_uint2(pack2(h[0],h[1]), pack2(h[2],h[3]));
  s.m = make_uint2(pack2(m[0],m[1]), pack2(m[2],m[3]));
  s.l = make_uint2(pack2(l[0],l[1]), pack2(l[2],l[3]));
  return s;
}

// ---- pre-pass: split W (fp32) into 3 bf16 planes, packed in MFMA B-fragment
// order.  Fragment id fid = et*128 + kc  (et = 16-expert tile, kc = K/32 chunk).
// Layout: wp[fid*1536 + s*512 + lane*8 .. +8] = W_split_s[et*16 + (lane&15)]
//                                               [kc*32 + (lane>>4)*8 .. +8]
// A wave reading one fragment does a single coalesced 1024 B load.
__global__ __launch_bounds__(256) void pack_w_kernel(
    const float* __restrict__ w, ushort* __restrict__ wp)
{
  const int g    = blockIdx.x * 256 + threadIdx.x;  // 65536 threads
  const int lane = g & 63;
  const int fid  = g >> 6;                          // 0..1023
  const int et   = fid >> 7;
  const int kc   = fid & 127;
  const int e    = et * 16 + (lane & 15);
  const int k0   = kc * 32 + (lane >> 4) * 8;
  const float4 x0 = *(const float4*)(w + (size_t)e * HIDDEN + k0);
  const float4 x1 = *(const float4*)(w + (size_t)e * HIDDEN + k0 + 4);
  Split3 s = split8(x0, x1);
  uint4* dst = (uint4*)wp + (size_t)fid * 3 * 64;
  dst[0 * 64 + lane] = s.h;
  dst[1 * 64 + lane] = s.m;
  dst[2 * 64 + lane] = s.l;
}

__global__ __launch_bounds__(512, 4) void router_kernel(
    const float*  __restrict__ h,     // [T, HIDDEN]
    const ushort* __restrict__ wp,    // packed split W (see pack_w_kernel)
    const float*  __restrict__ bias,  // [NEXP]
    float* __restrict__ out,          // [T*8] indices (as float) then [T*8] weights
    int T)
{
  __shared__ __align__(16) ushort smem_u[SMEM_USHORT];
  const int tid  = threadIdx.x;
  const int row0 = blockIdx.x * BM;

  // wave roles: wn = expert-column tile (32 experts), wk = K-parity half
  const int wid  = tid >> 6;
  const int wn   = wid & 3;
  const int wk   = wid >> 2;
  const int lane = tid & 63;
  const int lrow = lane & 15;   // MFMA row/col index within 16
  const int lk   = lane >> 4;   // MFMA k-group (8 contiguous k)

  // A staging: each thread owns 4 contiguous k of one token row
  const int sr = tid >> 4;      // token row 0..31
  const int sk = tid & 15;      // 4-float group along k
  const float* gA = h + (size_t)(row0 + sr) * HIDDEN + sk * 4;
  const int six   = (sr * 64 + sk * 4) ^ ((sr & 7) << 3);  // swizzled ushort idx

  f32x4 acc[2][2];
#pragma unroll
  for (int i = 0; i < 2; ++i)
#pragma unroll
    for (int j = 0; j < 2; ++j) acc[i][j] = (f32x4){0.f, 0.f, 0.f, 0.f};

  float4 pa = *(const float4*)(gA);   // prefetch chunk 0

  for (int c = 0; c < NCHUNK; ++c) {
    // ---- B fragments for this chunk: global -> register, L2-resident
    const int kc = c * 2 + wk;
    short8 bf[2][3];
#pragma unroll
    for (int ni = 0; ni < 2; ++ni) {
      const size_t fb = (size_t)((wn * 2 + ni) * 128 + kc) * 1536 + lane * 8;
#pragma unroll
      for (int s = 0; s < 3; ++s)
        bf[ni][s] = *(const short8*)(wp + fb + s * 512);
    }

    // ---- stage A(c) into buffer b (double-buffered: one barrier per chunk)
    const int b    = c & 1;
    const int abuf = b * 6144;
    {
      Split3x4 s = split4(pa);
      *(uint2*)(smem_u + abuf +    0 + six) = s.h;
      *(uint2*)(smem_u + abuf + 2048 + six) = s.m;
      *(uint2*)(smem_u + abuf + 4096 + six) = s.l;
    }
    if (c + 1 < NCHUNK) pa = *(const float4*)(gA + (c + 1) * BKC);
    __syncthreads();   // writers of buf b done; prior readers of buf b drained
                       // at the previous barrier (syncthreads drains lgkmcnt)

    // ---- A fragments from LDS (swizzled) + MFMA
    short8 af[2][3];
#pragma unroll
    for (int mi = 0; mi < 2; ++mi) {
      const int r  = mi * 16 + lrow;
      const int ix = (r * 64 + wk * 32 + lk * 8) ^ ((r & 7) << 3);
      af[mi][0] = *(const short8*)(smem_u + abuf +    0 + ix);
      af[mi][1] = *(const short8*)(smem_u + abuf + 2048 + ix);
      af[mi][2] = *(const short8*)(smem_u + abuf + 4096 + ix);
    }
#pragma unroll
    for (int mi = 0; mi < 2; ++mi)
#pragma unroll
      for (int ni = 0; ni < 2; ++ni) {
        f32x4 cc = acc[mi][ni];
        cc = __builtin_amdgcn_mfma_f32_16x16x32_bf16(af[mi][0], bf[ni][0], cc, 0, 0, 0);
        cc = __builtin_amdgcn_mfma_f32_16x16x32_bf16(af[mi][0], bf[ni][1], cc, 0, 0, 0);
        cc = __builtin_amdgcn_mfma_f32_16x16x32_bf16(af[mi][1], bf[ni][0], cc, 0, 0, 0);
        cc = __builtin_amdgcn_mfma_f32_16x16x32_bf16(af[mi][0], bf[ni][2], cc, 0, 0, 0);
        cc = __builtin_amdgcn_mfma_f32_16x16x32_bf16(af[mi][2], bf[ni][0], cc, 0, 0, 0);
        cc = __builtin_amdgcn_mfma_f32_16x16x32_bf16(af[mi][1], bf[ni][1], cc, 0, 0, 0);
        acc[mi][ni] = cc;
      }
  }

  // ---- combine wave-pair K-partials into score buffer (aliases A tiles)
  __syncthreads();
  float* Ss = (float*)smem_u;   // [32][SS]
  if (wk == 1) {
#pragma unroll
    for (int mi = 0; mi < 2; ++mi)
#pragma unroll
      for (int ni = 0; ni < 2; ++ni)
#pragma unroll
        for (int j = 0; j < 4; ++j)
          // D layout (m89): col = lane&15, row = (lane>>4)*4 + j
          Ss[(mi * 16 + lk * 4 + j) * SS + wn * 32 + ni * 16 + lrow] = acc[mi][ni][j];
  }
  __syncthreads();
  if (wk == 0) {
#pragma unroll
    for (int mi = 0; mi < 2; ++mi)
#pragma unroll
      for (int ni = 0; ni < 2; ++ni)
#pragma unroll
        for (int j = 0; j < 4; ++j) {
          const int ixs = (mi * 16 + lk * 4 + j) * SS + wn * 32 + ni * 16 + lrow;
          Ss[ixs] += acc[mi][ni][j];
        }
  }
  __syncthreads();

  // ---- top-k epilogue: wave wid handles tokens wid, wid+8, ...
  const float bb0 = bias[lane];
  const float bb1 = bias[lane + 64];

  for (int t = wid; t < BM; t += 8) {
    const float lg0 = Ss[t * SS + lane];
    const float lg1 = Ss[t * SS + 64 + lane];
    const float s0 = 1.0f / (1.0f + expf(-lg0));  // raw sigmoid score
    const float s1 = 1.0f / (1.0f + expf(-lg1));
    float c0 = s0 + bb0;                          // bias-corrected, for selection
    float c1 = s1 + bb1;

    int   sel_i[TOPK];
    float sel_r[TOPK];
    float rsum = 0.0f;
#pragma unroll
    for (int j = 0; j < TOPK; ++j) {
      const bool take0 = (c0 >= c1);
      float v  = take0 ? c0 : c1;
      float rr = take0 ? s0 : s1;
      int   ii = take0 ? lane : lane + 64;
#pragma unroll
      for (int off = 32; off > 0; off >>= 1) {
        const float ov  = __shfl_xor(v, off, 64);
        const float orr = __shfl_xor(rr, off, 64);
        const int   oi  = __shfl_xor(ii, off, 64);
        if (ov > v || (ov == v && oi < ii)) { v = ov; rr = orr; ii = oi; }
      }
      sel_i[j] = ii;
      sel_r[j] = rr;
      rsum += rr;
      if (ii == lane)      c0 = -__builtin_inff();
      if (ii == lane + 64) c1 = -__builtin_inff();
    }
    if (lane == 0) {
      const float inv = 1.0f / (rsum + 1e-20f);
      const size_t tok = (size_t)(row0 + t);
#pragma unroll
      for (int j = 0; j < TOPK; ++j) {
        out[tok * TOPK + j]                    = (float)sel_i[j];
        out[(size_t)T * TOPK + tok * TOPK + j] = sel_r[j] * inv;
      }
    }
  }
}

extern "C" void kernel_launch(void* const* d_in, const int* in_sizes, int n_in,
                              void* d_out, int out_size, void* d_ws, size_t ws_size,
                              hipStream_t stream) {
  const float* h    = (const float*)d_in[0];
  const float* w    = (const float*)d_in[1];
  const float* bias = (const float*)d_in[2];
  float* out = (float*)d_out;
  ushort* wp = (ushort*)d_ws;          // needs 1024*1536*2 B = 3 MiB
  const int T = in_sizes[0] / HIDDEN;  // 16384

  hipLaunchKernelGGL(pack_w_kernel, dim3(256), dim3(256), 0, stream, w, wp);

  dim3 grid(T / BM);   // 512 blocks -> 2 per CU
  dim3 block(512);     // 8 waves: 4 expert tiles x 2 K-halves
  hipLaunchKernelGGL(router_kernel, grid, block, 0, stream, h, wp, bias, out, T);
}

// Round 3
// 447.925 us; speedup vs baseline: 1.0017x; 1.0017x over previous
//
#include <hip/hip_runtime.h>
#include <math.h>

#define HIDDEN 4096
#define NEXP   128
#define TOPK   8
#define BM     32
#define BKC    64                  // K per staged chunk
#define NCHUNK (HIDDEN / BKC)      // 64
#define SS     132                 // padded stride for score rows in epilogue

// LDS (ushort units): A tiles double-buffered, 3 splits, [32][64] bf16 each.
//   buf b at b*6144, split s at s*2048. Total 12288 ushorts = 24 KiB.
//   Epilogue Ss[32][SS] floats (16.9 KiB) aliases the A region.
#define SMEM_USHORT 12288

typedef __attribute__((ext_vector_type(8))) short short8;  // 8 bf16 (4 VGPR)
typedef __attribute__((ext_vector_type(4))) float f32x4;   // MFMA accumulator

__device__ __forceinline__ unsigned pack2(unsigned a, unsigned b) {
  // low ushort = top16 of a, high ushort = top16 of b
  return (a >> 16) | (b & 0xFFFF0000u);
}

// Triple bf16 split: x = hi + mid + lo + O(2^-24 x). hi/mid round-half-away.
struct Split3 { uint4 h, m, l; };
__device__ __forceinline__ Split3 split8(float4 a, float4 b) {
  float x[8] = {a.x, a.y, a.z, a.w, b.x, b.y, b.z, b.w};
  unsigned h[8], m[8], l[8];
#pragma unroll
  for (int j = 0; j < 8; ++j) {
    unsigned u  = __float_as_uint(x[j]);
    unsigned hb = (u + 0x8000u) & 0xFFFF0000u;
    float rh    = x[j] - __uint_as_float(hb);
    unsigned um = __float_as_uint(rh);
    unsigned mb = (um + 0x8000u) & 0xFFFF0000u;
    float rm    = rh - __uint_as_float(mb);
    h[j] = hb; m[j] = mb; l[j] = __float_as_uint(rm);
  }
  Split3 s;
  s.h = make_uint4(pack2(h[0],h[1]), pack2(h[2],h[3]), pack2(h[4],h[5]), pack2(h[6],h[7]));
  s.m = make_uint4(pack2(m[0],m[1]), pack2(m[2],m[3]), pack2(m[4],m[5]), pack2(m[6],m[7]));
  s.l = make_uint4(pack2(l[0],l[1]), pack2(l[2],l[3]), pack2(l[4],l[5]), pack2(l[6],l[7]));
  return s;
}

struct Split3x4 { uint2 h, m, l; };
__device__ __forceinline__ Split3x4 split4(float4 a) {
  float x[4] = {a.x, a.y, a.z, a.w};
  unsigned h[4], m[4], l[4];
#pragma unroll
  for (int j = 0; j < 4; ++j) {
    unsigned u  = __float_as_uint(x[j]);
    unsigned hb = (u + 0x8000u) & 0xFFFF0000u;
    float rh    = x[j] - __uint_as_float(hb);
    unsigned um = __float_as_uint(rh);
    unsigned mb = (um + 0x8000u) & 0xFFFF0000u;
    float rm    = rh - __uint_as_float(mb);
    h[j] = hb; m[j] = mb; l[j] = __float_as_uint(rm);
  }
  Split3x4 s;
  s.h = make_uint2(pack2(h[0],h[1]), pack2(h[2],h[3]));
  s.m = make_uint2(pack2(m[0],m[1]), pack2(m[2],m[3]));
  s.l = make_uint2(pack2(l[0],l[1]), pack2(l[2],l[3]));
  return s;
}

// ---- pre-pass: split W (fp32) into 3 bf16 planes, packed in MFMA B-fragment
// order.  fid = et*128 + kc  (et = 16-expert tile, kc = K/32 chunk).
// wp[fid*1536 + s*512 + lane*8 ..] = W_split_s[et*16 + (lane&15)][kc*32 + (lane>>4)*8 ..]
__global__ __launch_bounds__(256) void pack_w_kernel(
    const float* __restrict__ w, ushort* __restrict__ wp)
{
  const int g    = blockIdx.x * 256 + threadIdx.x;  // 65536 threads
  const int lane = g & 63;
  const int fid  = g >> 6;                          // 0..1023
  const int et   = fid >> 7;
  const int kc   = fid & 127;
  const int e    = et * 16 + (lane & 15);
  const int k0   = kc * 32 + (lane >> 4) * 8;
  const float4 x0 = *(const float4*)(w + (size_t)e * HIDDEN + k0);
  const float4 x1 = *(const float4*)(w + (size_t)e * HIDDEN + k0 + 4);
  Split3 s = split8(x0, x1);
  uint4* dst = (uint4*)wp + (size_t)fid * 3 * 64;
  dst[0 * 64 + lane] = s.h;
  dst[1 * 64 + lane] = s.m;
  dst[2 * 64 + lane] = s.l;
}

__global__ __launch_bounds__(512, 4) void router_kernel(
    const float*  __restrict__ h,     // [T, HIDDEN]
    const ushort* __restrict__ wp,    // packed split W (see pack_w_kernel)
    const float*  __restrict__ bias,  // [NEXP]
    float* __restrict__ out,          // [T*8] indices (as float) then [T*8] weights
    int T)
{
  __shared__ __align__(16) ushort smem_u[SMEM_USHORT];
  const int tid  = threadIdx.x;
  const int row0 = blockIdx.x * BM;

  // wave roles: wn = expert-column tile (32 experts), wk = K-parity half
  const int wid  = tid >> 6;
  const int wn   = wid & 3;
  const int wk   = wid >> 2;
  const int lane = tid & 63;
  const int lrow = lane & 15;   // MFMA row/col index within 16
  const int lk   = lane >> 4;   // MFMA k-group (8 contiguous k)

  // A staging: each thread owns 4 contiguous k of one token row
  const int sr = tid >> 4;      // token row 0..31
  const int sk = tid & 15;      // 4-float group along k
  const float* gA = h + (size_t)(row0 + sr) * HIDDEN + sk * 4;
  const int six   = (sr * 64 + sk * 4) ^ ((sr & 7) << 3);  // swizzled ushort idx

  // A-fragment LDS offsets (constant across chunks; add buffer base at use)
  int aix[2];
#pragma unroll
  for (int mi = 0; mi < 2; ++mi) {
    const int r = mi * 16 + lrow;
    aix[mi] = (r * 64 + wk * 32 + lk * 8) ^ ((r & 7) << 3);
  }

  // per-lane B fragment pointers at chunk 0; advance 3072 ushorts per chunk
  const ushort* pB0 = wp + (size_t)((wn * 2 + 0) * 128 + wk) * 1536 + lane * 8;
  const ushort* pB1 = wp + (size_t)((wn * 2 + 1) * 128 + wk) * 1536 + lane * 8;

  f32x4 acc[2][2];
#pragma unroll
  for (int i = 0; i < 2; ++i)
#pragma unroll
    for (int j = 0; j < 2; ++j) acc[i][j] = (f32x4){0.f, 0.f, 0.f, 0.f};

  short8 bfA[2][3], bfB[2][3];   // ping-pong B fragment sets

  // ---- prologue: stage A(0), prefetch pa(1) and B(0)
  float4 pa = *(const float4*)(gA);            // pa(0)
  {
    Split3x4 s = split4(pa);
    *(uint2*)(smem_u +    0 + six) = s.h;
    *(uint2*)(smem_u + 2048 + six) = s.m;
    *(uint2*)(smem_u + 4096 + six) = s.l;
  }
  pa = *(const float4*)(gA + BKC);             // pa(1)
  const float* gA2 = gA + 2 * BKC;             // -> A(2)
#pragma unroll
  for (int s = 0; s < 3; ++s) {                // B(0) -> bfA
    bfA[0][s] = *(const short8*)(pB0 + s * 512);
    bfA[1][s] = *(const short8*)(pB1 + s * 512);
  }
  asm volatile("s_waitcnt lgkmcnt(0)" ::: "memory");
  __builtin_amdgcn_s_barrier();

  // body for one chunk: read A-frags from BR, prefetch next B into bfN,
  // stage A(next) into BW from pa, prefetch pa(next+1), MFMA with bfC.
  // Raw barrier + lgkmcnt(0) only: global loads stay in flight (T3/T4).
  auto body = [&](short8 (&bfC)[2][3], short8 (&bfN)[2][3],
                  const int BR, const int BW,
                  const bool prefB, const bool stageA, const bool prefA,
                  const bool bar) {
    short8 af[2][3];
#pragma unroll
    for (int mi = 0; mi < 2; ++mi) {
      af[mi][0] = *(const short8*)(smem_u + BR +    0 + aix[mi]);
      af[mi][1] = *(const short8*)(smem_u + BR + 2048 + aix[mi]);
      af[mi][2] = *(const short8*)(smem_u + BR + 4096 + aix[mi]);
    }
    if (prefB) {
      pB0 += 3072; pB1 += 3072;
#pragma unroll
      for (int s = 0; s < 3; ++s) {
        bfN[0][s] = *(const short8*)(pB0 + s * 512);
        bfN[1][s] = *(const short8*)(pB1 + s * 512);
      }
    }
    if (stageA) {
      Split3x4 s = split4(pa);
      *(uint2*)(smem_u + BW +    0 + six) = s.h;
      *(uint2*)(smem_u + BW + 2048 + six) = s.m;
      *(uint2*)(smem_u + BW + 4096 + six) = s.l;
    }
    if (prefA) { pa = *(const float4*)(gA2); gA2 += BKC; }
    __builtin_amdgcn_s_setprio(1);
#pragma unroll
    for (int mi = 0; mi < 2; ++mi)
#pragma unroll
      for (int ni = 0; ni < 2; ++ni) {
        f32x4 cc = acc[mi][ni];
        cc = __builtin_amdgcn_mfma_f32_16x16x32_bf16(af[mi][0], bfC[ni][0], cc, 0, 0, 0);
        cc = __builtin_amdgcn_mfma_f32_16x16x32_bf16(af[mi][0], bfC[ni][1], cc, 0, 0, 0);
        cc = __builtin_amdgcn_mfma_f32_16x16x32_bf16(af[mi][1], bfC[ni][0], cc, 0, 0, 0);
        cc = __builtin_amdgcn_mfma_f32_16x16x32_bf16(af[mi][0], bfC[ni][2], cc, 0, 0, 0);
        cc = __builtin_amdgcn_mfma_f32_16x16x32_bf16(af[mi][2], bfC[ni][0], cc, 0, 0, 0);
        cc = __builtin_amdgcn_mfma_f32_16x16x32_bf16(af[mi][1], bfC[ni][1], cc, 0, 0, 0);
        acc[mi][ni] = cc;
      }
    __builtin_amdgcn_s_setprio(0);
    if (bar) {
      asm volatile("s_waitcnt lgkmcnt(0)" ::: "memory");
      __builtin_amdgcn_s_barrier();
    }
  };

  // main loop: chunks 0..61 (body C consumes B(C), pa holds pa(C+1) at entry)
  for (int c = 0; c < NCHUNK - 2; c += 2) {
    body(bfA, bfB, 0,    6144, true, true, true, true);
    body(bfB, bfA, 6144, 0,    true, true, true, true);
  }
  // epilogue: chunks 62, 63
  body(bfA, bfB, 0,    6144, true,  true,  false, true);   // loads B(63), stages A(63)
  body(bfB, bfA, 6144, 0,    false, false, false, false);  // chunk 63

  // ---- combine wave-pair K-partials into score buffer (aliases A tiles)
  __syncthreads();
  float* Ss = (float*)smem_u;   // [32][SS]
  if (wk == 1) {
#pragma unroll
    for (int mi = 0; mi < 2; ++mi)
#pragma unroll
      for (int ni = 0; ni < 2; ++ni)
#pragma unroll
        for (int j = 0; j < 4; ++j)
          // D layout (m89): col = lane&15, row = (lane>>4)*4 + j
          Ss[(mi * 16 + lk * 4 + j) * SS + wn * 32 + ni * 16 + lrow] = acc[mi][ni][j];
  }
  __syncthreads();
  if (wk == 0) {
#pragma unroll
    for (int mi = 0; mi < 2; ++mi)
#pragma unroll
      for (int ni = 0; ni < 2; ++ni)
#pragma unroll
        for (int j = 0; j < 4; ++j) {
          const int ixs = (mi * 16 + lk * 4 + j) * SS + wn * 32 + ni * 16 + lrow;
          Ss[ixs] += acc[mi][ni][j];
        }
  }
  __syncthreads();

  // ---- top-k epilogue: wave wid handles tokens wid, wid+8, ...
  const float bb0 = bias[lane];
  const float bb1 = bias[lane + 64];

  for (int t = wid; t < BM; t += 8) {
    const float lg0 = Ss[t * SS + lane];
    const float lg1 = Ss[t * SS + 64 + lane];
    const float s0 = 1.0f / (1.0f + expf(-lg0));  // raw sigmoid score
    const float s1 = 1.0f / (1.0f + expf(-lg1));
    float c0 = s0 + bb0;                          // bias-corrected, for selection
    float c1 = s1 + bb1;

    int   sel_i[TOPK];
    float sel_r[TOPK];
    float rsum = 0.0f;
#pragma unroll
    for (int j = 0; j < TOPK; ++j) {
      const bool take0 = (c0 >= c1);
      float v  = take0 ? c0 : c1;
      float rr = take0 ? s0 : s1;
      int   ii = take0 ? lane : lane + 64;
#pragma unroll
      for (int off = 32; off > 0; off >>= 1) {
        const float ov  = __shfl_xor(v, off, 64);
        const float orr = __shfl_xor(rr, off, 64);
        const int   oi  = __shfl_xor(ii, off, 64);
        if (ov > v || (ov == v && oi < ii)) { v = ov; rr = orr; ii = oi; }
      }
      sel_i[j] = ii;
      sel_r[j] = rr;
      rsum += rr;
      if (ii == lane)      c0 = -__builtin_inff();
      if (ii == lane + 64) c1 = -__builtin_inff();
    }
    if (lane == 0) {
      const float inv = 1.0f / (rsum + 1e-20f);
      const size_t tok = (size_t)(row0 + t);
#pragma unroll
      for (int j = 0; j < TOPK; ++j) {
        out[tok * TOPK + j]                    = (float)sel_i[j];
        out[(size_t)T * TOPK + tok * TOPK + j] = sel_r[j] * inv;
      }
    }
  }
}

extern "C" void kernel_launch(void* const* d_in, const int* in_sizes, int n_in,
                              void* d_out, int out_size, void* d_ws, size_t ws_size,
                              hipStream_t stream) {
  const float* h    = (const float*)d_in[0];
  const float* w    = (const float*)d_in[1];
  const float* bias = (const float*)d_in[2];
  float* out = (float*)d_out;
  ushort* wp = (ushort*)d_ws;          // needs 1024*1536*2 B = 3 MiB
  const int T = in_sizes[0] / HIDDEN;  // 16384

  hipLaunchKernelGGL(pack_w_kernel, dim3(256), dim3(256), 0, stream, w, wp);

  dim3 grid(T / BM);   // 512 blocks -> 2 per CU
  dim3 block(512);     // 8 waves: 4 expert tiles x 2 K-halves
  hipLaunchKernelGGL(router_kernel, grid, block, 0, stream, h, wp, bias, out, T);
}